// Round 3
// baseline (194.553 us; speedup 1.0000x reference)
//
#include <hip/hip_runtime.h>
#include <hip/hip_bf16.h>
#include <stdint.h>

// B=16, T=2048, E=1024, H=128
typedef __attribute__((ext_vector_type(8))) short bf16x8;
typedef __attribute__((ext_vector_type(16))) float f32x16;
typedef __attribute__((ext_vector_type(4))) float f32x4;

__device__ __forceinline__ uint32_t cvt_pk_bf16(float a, float b){
  uint32_t r;
  asm volatile("v_cvt_pk_bf16_f32 %0, %1, %2" : "=v"(r) : "v"(a), "v"(b));
  return r;
}
__device__ __forceinline__ void permswap32(uint32_t &a, uint32_t &b){
  asm volatile("v_permlane32_swap_b32 %0, %1" : "+v"(a), "+v"(b));
}
__device__ __forceinline__ unsigned short f2bf(float f){
  uint32_t u = __float_as_uint(f);
  u += 0x7fff + ((u >> 16) & 1);   // RNE
  return (unsigned short)(u >> 16);
}

// Fragment-major layouts (1KB-contiguous per MFMA fragment load in attn):
//  QK: elem(b,t,h) -> (b*64 + t/32)*4096 + (h/16)*512 + (t%32)*16 + (h%16)
//  V : elem(b,s,h) -> ((b*64 + s/32)*4 + h/32)*1024 + ((s/16)%2)*512 + (h%32)*16 + (s%16)

// ---------------- Kernel 1: W -> Wt bf16 [384][1024]  (rows: 0-127 Q(scaled), 128-255 K, 256-383 V)
__global__ void prep_w(const float* __restrict__ Wk, const float* __restrict__ Wq,
                       const float* __restrict__ Wv, unsigned short* __restrict__ Wt){
  int idx = blockIdx.x * 256 + threadIdx.x;       // 0 .. 393215
  int mat = idx >> 17;
  int r = idx & 131071;                            // e*128 + h
  int h = r & 127;
  int e = r >> 7;
  const float* src = (mat == 0) ? Wq : (mat == 1) ? Wk : Wv;
  float v = src[r];
  if (mat == 0) v *= (1.4426950408889634f * 0.08838834764831845f); // log2e/sqrt(128)
  Wt[(mat * 128 + h) * 1024 + e] = f2bf(v);
}

// ---------------- Kernel 2: fused QKV projection GEMM.  BM=64, BN=384, BK=32.
#define LS 40   // padded LDS stride (elements)
__global__ __launch_bounds__(256, 2) void proj_gemm(
    const float* __restrict__ x, const unsigned short* __restrict__ Wt,
    unsigned short* __restrict__ Qb, unsigned short* __restrict__ Kb,
    unsigned short* __restrict__ Vt){
  __shared__ __align__(16) unsigned short As[64 * LS];
  __shared__ __align__(16) unsigned short Bs[384 * LS];
  const int tid  = threadIdx.x;
  const int lane = tid & 63;
  const int w    = tid >> 6;        // wave 0..3 = column group
  const int lr   = lane & 15;
  const int lk   = lane >> 4;       // 0..3
  const int m0   = blockIdx.x * 64; // token-tile base (flat M=32768)

  f32x4 acc[4][6];
  #pragma unroll
  for (int i = 0; i < 4; ++i)
    #pragma unroll
    for (int jj = 0; jj < 6; ++jj) acc[i][jj] = (f32x4){0.f, 0.f, 0.f, 0.f};

  float4 areg[2];
  bf16x8 breg[6];
  // prefetch ks=0
  #pragma unroll
  for (int i = 0; i < 2; ++i){
    int idx = i * 256 + tid; int row = idx >> 3, kp = idx & 7;
    areg[i] = *(const float4*)(x + (size_t)(m0 + row) * 1024 + kp * 4);
  }
  #pragma unroll
  for (int i = 0; i < 6; ++i){
    int idx = i * 256 + tid; int row = idx >> 2, pp = idx & 3;
    breg[i] = *(const bf16x8*)(Wt + (size_t)row * 1024 + pp * 8);
  }

  for (int ks = 0; ks < 32; ++ks){
    __syncthreads();
    #pragma unroll
    for (int i = 0; i < 2; ++i){
      int idx = i * 256 + tid; int row = idx >> 3, kp = idx & 7;
      uint32_t lo = cvt_pk_bf16(areg[i].x, areg[i].y);
      uint32_t hi = cvt_pk_bf16(areg[i].z, areg[i].w);
      *(uint2*)((char*)As + row * (LS * 2) + kp * 8) = make_uint2(lo, hi);
    }
    #pragma unroll
    for (int i = 0; i < 6; ++i){
      int idx = i * 256 + tid; int row = idx >> 2, pp = idx & 3;
      *(bf16x8*)((char*)Bs + row * (LS * 2) + pp * 16) = breg[i];
    }
    __syncthreads();
    if (ks + 1 < 32){
      int ko = (ks + 1) * 32;
      #pragma unroll
      for (int i = 0; i < 2; ++i){
        int idx = i * 256 + tid; int row = idx >> 3, kp = idx & 7;
        areg[i] = *(const float4*)(x + (size_t)(m0 + row) * 1024 + ko + kp * 4);
      }
      #pragma unroll
      for (int i = 0; i < 6; ++i){
        int idx = i * 256 + tid; int row = idx >> 2, pp = idx & 3;
        breg[i] = *(const bf16x8*)(Wt + (size_t)row * 1024 + ko + pp * 8);
      }
    }
    bf16x8 af[4], bfr[6];
    #pragma unroll
    for (int am = 0; am < 4; ++am)
      af[am] = *(const bf16x8*)((char*)As + (am * 16 + lr) * (LS * 2) + lk * 16);
    #pragma unroll
    for (int bn = 0; bn < 6; ++bn)
      bfr[bn] = *(const bf16x8*)((char*)Bs + (w * 96 + bn * 16 + lr) * (LS * 2) + lk * 16);
    #pragma unroll
    for (int am = 0; am < 4; ++am)
      #pragma unroll
      for (int bn = 0; bn < 6; ++bn)
        acc[am][bn] = __builtin_amdgcn_mfma_f32_16x16x32_bf16(af[am], bfr[bn], acc[am][bn], 0, 0, 0);
  }

  const int b  = m0 >> 11;
  const int t0 = m0 & 2047;
  #pragma unroll
  for (int am = 0; am < 4; ++am){
    #pragma unroll
    for (int bn = 0; bn < 6; ++bn){
      int c0   = w * 96 + bn * 16;
      int mat  = c0 >> 7;
      int hcol = (c0 & 127) + lr;
      int tr   = t0 + am * 16 + lk * 4;    // D: row=(lane>>4)*4+j, col=lane&15
      f32x4 v = acc[am][bn];
      if (mat <= 1){
        unsigned short* dst = (mat == 0) ? Qb : Kb;
        // fragment-major QK store
        size_t base = (size_t)(b * 64 + (tr >> 5)) * 4096 + (size_t)(hcol >> 4) * 512 + (hcol & 15);
        #pragma unroll
        for (int jj = 0; jj < 4; ++jj)
          dst[base + (size_t)((tr + jj) & 31) * 16] = f2bf(v[jj]);
      } else { // V fragment-major: 4 consecutive s -> 8B store
        ushort4 pk;
        pk.x = f2bf(v[0]); pk.y = f2bf(v[1]); pk.z = f2bf(v[2]); pk.w = f2bf(v[3]);
        size_t addr = (size_t)((b * 64 + (tr >> 5)) * 4 + (hcol >> 5)) * 1024
                    + (size_t)((tr >> 4) & 1) * 512 + (size_t)(hcol & 31) * 16 + (tr & 15);
        *(ushort4*)(Vt + addr) = pk;
      }
    }
  }
}

// ---------------- Kernel 3: causal flash attention, swapped-QK 32x32x16.
// 1024 blocks, 4 waves = 4-way kv split, scale-then-sum combine (17.9KB LDS).
// Per-CU balanced chunk map: each CU's 4 chunks sum to exactly 130 tiles.
__global__ __launch_bounds__(256, 4) void attn(
    const unsigned short* __restrict__ Qf, const unsigned short* __restrict__ Kf,
    const unsigned short* __restrict__ Vf, float* __restrict__ out){
  __shared__ float comb[32][132];
  __shared__ float msh[4][32];
  __shared__ float lsh[4][32];

  const int tid  = threadIdx.x;
  const int lane = tid & 63;
  const int w    = tid >> 6;            // kv-split index 0..3
  const int bid  = blockIdx.x;
  const int xcd  = bid & 7;
  const int k    = bid >> 3;            // 0..127 within XCD
  const int a    = k & 31;
  const int mdx  = k >> 5;              // 0..3
  const int b    = xcd * 2 + (mdx >> 1);
  const int c    = (mdx & 1) ? a : 63 - a;   // per-CU sets {63-a, a} x 2 batches
  const int r0   = c * 32;
  const int q5   = lane & 31;
  const int hi   = lane >> 5;

  bf16x8 qf[8];
  const unsigned short* qp = Qf + (size_t)(b * 64 + c) * 4096 + q5 * 16 + hi * 8;
  #pragma unroll
  for (int f = 0; f < 8; ++f) qf[f] = *(const bf16x8*)(qp + f * 512);

  f32x16 oacc[4];
  #pragma unroll
  for (int i = 0; i < 4; ++i) oacc[i] = (f32x16)(0.f);
  float m = -1e30f, l = 0.f;

  const unsigned short* kb = Kf + (size_t)b * 64 * 4096;
  const unsigned short* vb = Vf + (size_t)b * 64 * 4096;

  bf16x8 kf[8];
  if (w <= c){
    const unsigned short* kp = kb + (size_t)w * 4096 + q5 * 16 + hi * 8;
    #pragma unroll
    for (int f = 0; f < 8; ++f) kf[f] = *(const bf16x8*)(kp + f * 512);
  }

  for (int t = w; t <= c; t += 4){
    f32x16 sacc = (f32x16)(0.f);   // S^T[s][q] = sum_h K[s][h] Q[q][h]
    #pragma unroll
    for (int f = 0; f < 8; ++f)
      sacc = __builtin_amdgcn_mfma_f32_32x32x16_bf16(kf[f], qf[f], sacc, 0, 0, 0);
    // prefetch next K tile (overlaps softmax+PV)
    if (t + 4 <= c){
      const unsigned short* kp = kb + (size_t)(t + 4) * 4096 + q5 * 16 + hi * 8;
      #pragma unroll
      for (int f = 0; f < 8; ++f) kf[f] = *(const bf16x8*)(kp + f * 512);
    }
    // V fragments (contiguous 1KB per instr), issued before softmax
    bf16x8 vf[8];
    const unsigned short* vp = vb + (size_t)t * 4096 + q5 * 16 + hi * 8;
    #pragma unroll
    for (int ht = 0; ht < 4; ++ht)
      #pragma unroll
      for (int sf = 0; sf < 2; ++sf)
        vf[ht * 2 + sf] = *(const bf16x8*)(vp + ht * 1024 + sf * 512);

    float sv[16];
    #pragma unroll
    for (int r = 0; r < 16; ++r) sv[r] = sacc[r];
    if (t == c){   // diagonal tile: mask s>q  (row = (r&3)+8*(r>>2)+4*hi, col q = q5)
      #pragma unroll
      for (int r = 0; r < 16; ++r){
        int srow = (r & 3) + 8 * (r >> 2) + 4 * hi;
        if (srow > q5) sv[r] = -1e30f;
      }
    }
    float pm = sv[0];
    #pragma unroll
    for (int r = 1; r < 16; ++r) pm = fmaxf(pm, sv[r]);
    pm = fmaxf(pm, __shfl_xor(pm, 32));
    if (!__all(pm - m <= 8.0f)){   // defer-max (log2 domain)
      float mn = fmaxf(m, pm);
      float al = exp2f(m - mn);
      #pragma unroll
      for (int i = 0; i < 4; ++i) oacc[i] *= al;
      l *= al;
      m = mn;
    }
    float pv[16]; float ts = 0.f;
    #pragma unroll
    for (int r = 0; r < 16; ++r){ pv[r] = exp2f(sv[r] - m); ts += pv[r]; }
    ts += __shfl_xor(ts, 32);
    l += ts;
    // P^T -> bf16 B-frags: cvt_pk + permlane32_swap (fills both k-halves)
    uint32_t w0 = cvt_pk_bf16(pv[0],  pv[1]);
    uint32_t w2 = cvt_pk_bf16(pv[4],  pv[5]);  permswap32(w0, w2);
    uint32_t w1 = cvt_pk_bf16(pv[2],  pv[3]);
    uint32_t w3 = cvt_pk_bf16(pv[6],  pv[7]);  permswap32(w1, w3);
    uint32_t w4 = cvt_pk_bf16(pv[8],  pv[9]);
    uint32_t w6 = cvt_pk_bf16(pv[12], pv[13]); permswap32(w4, w6);
    uint32_t w5 = cvt_pk_bf16(pv[10], pv[11]);
    uint32_t w7 = cvt_pk_bf16(pv[14], pv[15]); permswap32(w5, w7);
    union { uint32_t u[4]; bf16x8 v; } pf0u, pf1u;
    pf0u.u[0] = w0; pf0u.u[1] = w1; pf0u.u[2] = w2; pf0u.u[3] = w3;
    pf1u.u[0] = w4; pf1u.u[1] = w5; pf1u.u[2] = w6; pf1u.u[3] = w7;
    #pragma unroll
    for (int ht = 0; ht < 4; ++ht){   // O^T[h][q] += V^T · P^T
      oacc[ht] = __builtin_amdgcn_mfma_f32_32x32x16_bf16(vf[ht * 2 + 0], pf0u.v, oacc[ht], 0, 0, 0);
      oacc[ht] = __builtin_amdgcn_mfma_f32_32x32x16_bf16(vf[ht * 2 + 1], pf1u.v, oacc[ht], 0, 0, 0);
    }
  }

  // -------- scale-then-sum combine --------
  if (hi == 0){ msh[w][q5] = m; lsh[w][q5] = l; }
  __syncthreads();
  {
    float mv0 = msh[0][q5], mv1 = msh[1][q5], mv2 = msh[2][q5], mv3 = msh[3][q5];
    float lv0 = lsh[0][q5], lv1 = lsh[1][q5], lv2 = lsh[2][q5], lv3 = lsh[3][q5];
    float mfm = fmaxf(fmaxf(mv0, mv1), fmaxf(mv2, mv3));
    float lf  = lv0 * exp2f(mv0 - mfm) + lv1 * exp2f(mv1 - mfm)
              + lv2 * exp2f(mv2 - mfm) + lv3 * exp2f(mv3 - mfm);
    float s = exp2f(m - mfm) / lf;
    #pragma unroll
    for (int ht = 0; ht < 4; ++ht) oacc[ht] *= s;
  }
  // serial RMW accumulate into comb (wave 0 writes, 1..3 add)
  #pragma unroll 1
  for (int rr = 0; rr < 4; ++rr){
    if (w == rr){
      #pragma unroll
      for (int ht = 0; ht < 4; ++ht)
        #pragma unroll
        for (int r4 = 0; r4 < 4; ++r4){
          int hh = ht * 32 + 8 * r4 + 4 * hi;
          float4 add;
          add.x = oacc[ht][r4 * 4 + 0]; add.y = oacc[ht][r4 * 4 + 1];
          add.z = oacc[ht][r4 * 4 + 2]; add.w = oacc[ht][r4 * 4 + 3];
          float* p = &comb[q5][hh];
          if (rr == 0) *(float4*)p = add;
          else { float4 cur = *(const float4*)p;
                 cur.x += add.x; cur.y += add.y; cur.z += add.z; cur.w += add.w;
                 *(float4*)p = cur; }
        }
    }
    __syncthreads();
  }
  // cooperative coalesced store: 32 rows x 128 f32
  float* obase = out + ((size_t)b * 2048 + r0) * 128;
  #pragma unroll
  for (int it = 0; it < 4; ++it){
    int row = it * 8 + (tid >> 5);
    int col = (tid & 31) * 4;
    *(float4*)(obase + row * 128 + col) = *(const float4*)&comb[row][col];
  }
}

extern "C" void kernel_launch(void* const* d_in, const int* in_sizes, int n_in,
                              void* d_out, int out_size, void* d_ws, size_t ws_size,
                              hipStream_t stream){
  const float* x  = (const float*)d_in[0];
  // d_in[1] = mask : causal tril by construction, applied structurally
  const float* Wk = (const float*)d_in[2];
  const float* Wq = (const float*)d_in[3];
  const float* Wv = (const float*)d_in[4];
  char* ws = (char*)d_ws;
  unsigned short* Wt = (unsigned short*)(ws);                    // 768 KB
  unsigned short* Qb = (unsigned short*)(ws + (1ull  << 20));    // 8 MB
  unsigned short* Kb = (unsigned short*)(ws + (9ull  << 20));    // 8 MB
  unsigned short* Vt = (unsigned short*)(ws + (17ull << 20));    // 8 MB
  float* out = (float*)d_out;

  hipLaunchKernelGGL(prep_w,    dim3(1536), dim3(256), 0, stream, Wk, Wq, Wv, Wt);
  hipLaunchKernelGGL(proj_gemm, dim3(512),  dim3(256), 0, stream, x, Wt, Qb, Kb, Vt);
  hipLaunchKernelGGL(attn,      dim3(1024), dim3(256), 0, stream, Qb, Kb, Vt, out);
}

// Round 4
// 89.073 us; speedup vs baseline: 2.1842x; 2.1842x over previous
//
#include <hip/hip_runtime.h>
#include <hip/hip_bf16.h>
#include <stdint.h>

// B=16, T=2048, E=1024, H=128
typedef __attribute__((ext_vector_type(8))) short bf16x8;
typedef __attribute__((ext_vector_type(16))) float f32x16;
typedef __attribute__((ext_vector_type(4))) float f32x4;

__device__ __forceinline__ uint32_t cvt_pk_bf16(float a, float b){
  uint32_t r;
  asm volatile("v_cvt_pk_bf16_f32 %0, %1, %2" : "=v"(r) : "v"(a), "v"(b));
  return r;
}
__device__ __forceinline__ void permswap32(uint32_t &a, uint32_t &b){
  asm volatile("v_permlane32_swap_b32 %0, %1" : "+v"(a), "+v"(b));
}
__device__ __forceinline__ unsigned short f2bf(float f){
  uint32_t u = __float_as_uint(f);
  u += 0x7fff + ((u >> 16) & 1);   // RNE
  return (unsigned short)(u >> 16);
}

// Fragment-major layouts (1KB-contiguous per MFMA fragment load in attn):
//  QK: elem(b,t,h) -> (b*64 + t/32)*4096 + (h/16)*512 + (t%32)*16 + (h%16)
//  V : elem(b,s,h) -> ((b*64 + s/32)*4 + h/32)*1024 + ((s/16)%2)*512 + (h%32)*16 + (s%16)

// ---------------- Kernel 1: W -> Wt bf16 [384][1024]  (rows: 0-127 Q(scaled), 128-255 K, 256-383 V)
__global__ void prep_w(const float* __restrict__ Wk, const float* __restrict__ Wq,
                       const float* __restrict__ Wv, unsigned short* __restrict__ Wt){
  int idx = blockIdx.x * 256 + threadIdx.x;       // 0 .. 393215
  int mat = idx >> 17;
  int r = idx & 131071;                            // e*128 + h
  int h = r & 127;
  int e = r >> 7;
  const float* src = (mat == 0) ? Wq : (mat == 1) ? Wk : Wv;
  float v = src[r];
  if (mat == 0) v *= (1.4426950408889634f * 0.08838834764831845f); // log2e/sqrt(128)
  Wt[(mat * 128 + h) * 1024 + e] = f2bf(v);
}

// ---------------- Kernel 2: fused QKV projection GEMM.  BM=64, BN=384, BK=32.
#define LS 40   // padded LDS stride (elements)
__global__ __launch_bounds__(256, 2) void proj_gemm(
    const float* __restrict__ x, const unsigned short* __restrict__ Wt,
    unsigned short* __restrict__ Qb, unsigned short* __restrict__ Kb,
    unsigned short* __restrict__ Vt){
  __shared__ __align__(16) unsigned short As[64 * LS];
  __shared__ __align__(16) unsigned short Bs[384 * LS];
  const int tid  = threadIdx.x;
  const int lane = tid & 63;
  const int w    = tid >> 6;        // wave 0..3 = column group
  const int lr   = lane & 15;
  const int lk   = lane >> 4;       // 0..3
  const int m0   = blockIdx.x * 64; // token-tile base (flat M=32768)

  f32x4 acc[4][6];
  #pragma unroll
  for (int i = 0; i < 4; ++i)
    #pragma unroll
    for (int jj = 0; jj < 6; ++jj) acc[i][jj] = (f32x4){0.f, 0.f, 0.f, 0.f};

  float4 areg[2];
  bf16x8 breg[6];
  // prefetch ks=0
  #pragma unroll
  for (int i = 0; i < 2; ++i){
    int idx = i * 256 + tid; int row = idx >> 3, kp = idx & 7;
    areg[i] = *(const float4*)(x + (size_t)(m0 + row) * 1024 + kp * 4);
  }
  #pragma unroll
  for (int i = 0; i < 6; ++i){
    int idx = i * 256 + tid; int row = idx >> 2, pp = idx & 3;
    breg[i] = *(const bf16x8*)(Wt + (size_t)row * 1024 + pp * 8);
  }

  for (int ks = 0; ks < 32; ++ks){
    __syncthreads();
    #pragma unroll
    for (int i = 0; i < 2; ++i){
      int idx = i * 256 + tid; int row = idx >> 3, kp = idx & 7;
      uint32_t lo = cvt_pk_bf16(areg[i].x, areg[i].y);
      uint32_t hi = cvt_pk_bf16(areg[i].z, areg[i].w);
      *(uint2*)((char*)As + row * (LS * 2) + kp * 8) = make_uint2(lo, hi);
    }
    #pragma unroll
    for (int i = 0; i < 6; ++i){
      int idx = i * 256 + tid; int row = idx >> 2, pp = idx & 3;
      *(bf16x8*)((char*)Bs + row * (LS * 2) + pp * 16) = breg[i];
    }
    __syncthreads();
    if (ks + 1 < 32){
      int ko = (ks + 1) * 32;
      #pragma unroll
      for (int i = 0; i < 2; ++i){
        int idx = i * 256 + tid; int row = idx >> 3, kp = idx & 7;
        areg[i] = *(const float4*)(x + (size_t)(m0 + row) * 1024 + ko + kp * 4);
      }
      #pragma unroll
      for (int i = 0; i < 6; ++i){
        int idx = i * 256 + tid; int row = idx >> 2, pp = idx & 3;
        breg[i] = *(const bf16x8*)(Wt + (size_t)row * 1024 + ko + pp * 8);
      }
    }
    bf16x8 af[4], bfr[6];
    #pragma unroll
    for (int am = 0; am < 4; ++am)
      af[am] = *(const bf16x8*)((char*)As + (am * 16 + lr) * (LS * 2) + lk * 16);
    #pragma unroll
    for (int bn = 0; bn < 6; ++bn)
      bfr[bn] = *(const bf16x8*)((char*)Bs + (w * 96 + bn * 16 + lr) * (LS * 2) + lk * 16);
    #pragma unroll
    for (int am = 0; am < 4; ++am)
      #pragma unroll
      for (int bn = 0; bn < 6; ++bn)
        acc[am][bn] = __builtin_amdgcn_mfma_f32_16x16x32_bf16(af[am], bfr[bn], acc[am][bn], 0, 0, 0);
  }

  const int b  = m0 >> 11;
  const int t0 = m0 & 2047;
  #pragma unroll
  for (int am = 0; am < 4; ++am){
    #pragma unroll
    for (int bn = 0; bn < 6; ++bn){
      int c0   = w * 96 + bn * 16;
      int mat  = c0 >> 7;
      int hcol = (c0 & 127) + lr;
      int tr   = t0 + am * 16 + lk * 4;    // D: row=(lane>>4)*4+j, col=lane&15
      f32x4 v = acc[am][bn];
      if (mat <= 1){
        unsigned short* dst = (mat == 0) ? Qb : Kb;
        // fragment-major QK store
        size_t base = (size_t)(b * 64 + (tr >> 5)) * 4096 + (size_t)(hcol >> 4) * 512 + (hcol & 15);
        #pragma unroll
        for (int jj = 0; jj < 4; ++jj)
          dst[base + (size_t)((tr + jj) & 31) * 16] = f2bf(v[jj]);
      } else { // V fragment-major: 4 consecutive s -> 8B store
        ushort4 pk;
        pk.x = f2bf(v[0]); pk.y = f2bf(v[1]); pk.z = f2bf(v[2]); pk.w = f2bf(v[3]);
        size_t addr = (size_t)((b * 64 + (tr >> 5)) * 4 + (hcol >> 5)) * 1024
                    + (size_t)((tr >> 4) & 1) * 512 + (size_t)(hcol & 31) * 16 + (tr & 15);
        *(ushort4*)(Vt + addr) = pk;
      }
    }
  }
}

// ---------------- Kernel 3: causal flash attention, swapped-QK 32x32x16.
// 1024 blocks, 4 waves = 4-way kv split, scale-then-sum combine (17.9KB LDS).
// launch_bounds(256,2): 256-VGPR budget -> NO SPILL (R3's (256,4) spilled oacc to scratch).
__global__ __launch_bounds__(256, 2) void attn(
    const unsigned short* __restrict__ Qf, const unsigned short* __restrict__ Kf,
    const unsigned short* __restrict__ Vf, float* __restrict__ out){
  __shared__ float comb[32][132];
  __shared__ float msh[4][32];
  __shared__ float lsh[4][32];

  const int tid  = threadIdx.x;
  const int lane = tid & 63;
  const int w    = tid >> 6;            // kv-split index 0..3
  const int bid  = blockIdx.x;
  const int xcd  = bid & 7;
  const int k    = bid >> 3;            // 0..127 within XCD
  const int a    = k & 31;
  const int mdx  = k >> 5;              // 0..3
  const int b    = xcd * 2 + (mdx >> 1);
  const int c    = (mdx & 1) ? a : 63 - a;   // per-CU sets {63-a, a} x 2 batches
  const int r0   = c * 32;
  const int q5   = lane & 31;
  const int hi   = lane >> 5;

  bf16x8 qf[8];
  const unsigned short* qp = Qf + (size_t)(b * 64 + c) * 4096 + q5 * 16 + hi * 8;
  #pragma unroll
  for (int f = 0; f < 8; ++f) qf[f] = *(const bf16x8*)(qp + f * 512);

  f32x16 oacc[4];
  #pragma unroll
  for (int i = 0; i < 4; ++i) oacc[i] = (f32x16)(0.f);
  float m = -1e30f, l = 0.f;

  const unsigned short* kb = Kf + (size_t)b * 64 * 4096;
  const unsigned short* vb = Vf + (size_t)b * 64 * 4096;

  bf16x8 kf[8];
  if (w <= c){
    const unsigned short* kp = kb + (size_t)w * 4096 + q5 * 16 + hi * 8;
    #pragma unroll
    for (int f = 0; f < 8; ++f) kf[f] = *(const bf16x8*)(kp + f * 512);
  }

  for (int t = w; t <= c; t += 4){
    f32x16 sacc = (f32x16)(0.f);   // S^T[s][q] = sum_h K[s][h] Q[q][h]
    #pragma unroll
    for (int f = 0; f < 8; ++f)
      sacc = __builtin_amdgcn_mfma_f32_32x32x16_bf16(kf[f], qf[f], sacc, 0, 0, 0);
    // prefetch next K tile (overlaps softmax+PV)
    if (t + 4 <= c){
      const unsigned short* kp = kb + (size_t)(t + 4) * 4096 + q5 * 16 + hi * 8;
      #pragma unroll
      for (int f = 0; f < 8; ++f) kf[f] = *(const bf16x8*)(kp + f * 512);
    }
    // V fragments (contiguous 1KB per instr), issued before softmax
    bf16x8 vf[8];
    const unsigned short* vp = vb + (size_t)t * 4096 + q5 * 16 + hi * 8;
    #pragma unroll
    for (int ht = 0; ht < 4; ++ht)
      #pragma unroll
      for (int sf = 0; sf < 2; ++sf)
        vf[ht * 2 + sf] = *(const bf16x8*)(vp + ht * 1024 + sf * 512);

    float sv[16];
    #pragma unroll
    for (int r = 0; r < 16; ++r) sv[r] = sacc[r];
    if (t == c){   // diagonal tile: mask s>q  (row = (r&3)+8*(r>>2)+4*hi, col q = q5)
      #pragma unroll
      for (int r = 0; r < 16; ++r){
        int srow = (r & 3) + 8 * (r >> 2) + 4 * hi;
        if (srow > q5) sv[r] = -1e30f;
      }
    }
    float pm = sv[0];
    #pragma unroll
    for (int r = 1; r < 16; ++r) pm = fmaxf(pm, sv[r]);
    pm = fmaxf(pm, __shfl_xor(pm, 32));
    if (!__all(pm - m <= 8.0f)){   // defer-max (log2 domain)
      float mn = fmaxf(m, pm);
      float al = exp2f(m - mn);
      #pragma unroll
      for (int i = 0; i < 4; ++i) oacc[i] *= al;
      l *= al;
      m = mn;
    }
    float pv[16]; float ts = 0.f;
    #pragma unroll
    for (int r = 0; r < 16; ++r){ pv[r] = exp2f(sv[r] - m); ts += pv[r]; }
    ts += __shfl_xor(ts, 32);
    l += ts;
    // P^T -> bf16 B-frags: cvt_pk + permlane32_swap (fills both k-halves)
    uint32_t w0 = cvt_pk_bf16(pv[0],  pv[1]);
    uint32_t w2 = cvt_pk_bf16(pv[4],  pv[5]);  permswap32(w0, w2);
    uint32_t w1 = cvt_pk_bf16(pv[2],  pv[3]);
    uint32_t w3 = cvt_pk_bf16(pv[6],  pv[7]);  permswap32(w1, w3);
    uint32_t w4 = cvt_pk_bf16(pv[8],  pv[9]);
    uint32_t w6 = cvt_pk_bf16(pv[12], pv[13]); permswap32(w4, w6);
    uint32_t w5 = cvt_pk_bf16(pv[10], pv[11]);
    uint32_t w7 = cvt_pk_bf16(pv[14], pv[15]); permswap32(w5, w7);
    union { uint32_t u[4]; bf16x8 v; } pf0u, pf1u;
    pf0u.u[0] = w0; pf0u.u[1] = w1; pf0u.u[2] = w2; pf0u.u[3] = w3;
    pf1u.u[0] = w4; pf1u.u[1] = w5; pf1u.u[2] = w6; pf1u.u[3] = w7;
    #pragma unroll
    for (int ht = 0; ht < 4; ++ht){   // O^T[h][q] += V^T · P^T
      oacc[ht] = __builtin_amdgcn_mfma_f32_32x32x16_bf16(vf[ht * 2 + 0], pf0u.v, oacc[ht], 0, 0, 0);
      oacc[ht] = __builtin_amdgcn_mfma_f32_32x32x16_bf16(vf[ht * 2 + 1], pf1u.v, oacc[ht], 0, 0, 0);
    }
  }

  // -------- scale-then-sum combine --------
  if (hi == 0){ msh[w][q5] = m; lsh[w][q5] = l; }
  __syncthreads();
  {
    float mv0 = msh[0][q5], mv1 = msh[1][q5], mv2 = msh[2][q5], mv3 = msh[3][q5];
    float lv0 = lsh[0][q5], lv1 = lsh[1][q5], lv2 = lsh[2][q5], lv3 = lsh[3][q5];
    float mfm = fmaxf(fmaxf(mv0, mv1), fmaxf(mv2, mv3));
    float lf  = lv0 * exp2f(mv0 - mfm) + lv1 * exp2f(mv1 - mfm)
              + lv2 * exp2f(mv2 - mfm) + lv3 * exp2f(mv3 - mfm);
    float s = exp2f(m - mfm) / lf;
    #pragma unroll
    for (int ht = 0; ht < 4; ++ht) oacc[ht] *= s;
  }
  // serial RMW accumulate into comb (wave 0 writes, 1..3 add)
  #pragma unroll 1
  for (int rr = 0; rr < 4; ++rr){
    if (w == rr){
      #pragma unroll
      for (int ht = 0; ht < 4; ++ht)
        #pragma unroll
        for (int r4 = 0; r4 < 4; ++r4){
          int hh = ht * 32 + 8 * r4 + 4 * hi;
          float4 add;
          add.x = oacc[ht][r4 * 4 + 0]; add.y = oacc[ht][r4 * 4 + 1];
          add.z = oacc[ht][r4 * 4 + 2]; add.w = oacc[ht][r4 * 4 + 3];
          float* p = &comb[q5][hh];
          if (rr == 0) *(float4*)p = add;
          else { float4 cur = *(const float4*)p;
                 cur.x += add.x; cur.y += add.y; cur.z += add.z; cur.w += add.w;
                 *(float4*)p = cur; }
        }
    }
    __syncthreads();
  }
  // cooperative coalesced store: 32 rows x 128 f32
  float* obase = out + ((size_t)b * 2048 + r0) * 128;
  #pragma unroll
  for (int it = 0; it < 4; ++it){
    int row = it * 8 + (tid >> 5);
    int col = (tid & 31) * 4;
    *(float4*)(obase + row * 128 + col) = *(const float4*)&comb[row][col];
  }
}

extern "C" void kernel_launch(void* const* d_in, const int* in_sizes, int n_in,
                              void* d_out, int out_size, void* d_ws, size_t ws_size,
                              hipStream_t stream){
  const float* x  = (const float*)d_in[0];
  // d_in[1] = mask : causal tril by construction, applied structurally
  const float* Wk = (const float*)d_in[2];
  const float* Wq = (const float*)d_in[3];
  const float* Wv = (const float*)d_in[4];
  char* ws = (char*)d_ws;
  unsigned short* Wt = (unsigned short*)(ws);                    // 768 KB
  unsigned short* Qb = (unsigned short*)(ws + (1ull  << 20));    // 8 MB
  unsigned short* Kb = (unsigned short*)(ws + (9ull  << 20));    // 8 MB
  unsigned short* Vt = (unsigned short*)(ws + (17ull << 20));    // 8 MB
  float* out = (float*)d_out;

  hipLaunchKernelGGL(prep_w,    dim3(1536), dim3(256), 0, stream, Wk, Wq, Wv, Wt);
  hipLaunchKernelGGL(proj_gemm, dim3(512),  dim3(256), 0, stream, x, Wt, Qb, Kb, Vt);
  hipLaunchKernelGGL(attn,      dim3(1024), dim3(256), 0, stream, Qb, Kb, Vt, out);
}